// Round 1
// baseline (10608.831 us; speedup 1.0000x reference)
//
#include <hip/hip_runtime.h>
#include <hip/hip_bf16.h>

// ---- model dims ----
#define BB   8
#define TT   256
#define DIN  53
#define DD   768
#define HH   12
#define DHD  64
#define FF_  3072
#define LL   4
#define KK   1024
#define QKVD 2304
#define BN_F 0.9999950000374997f  // 1/sqrt(1+1e-5)

__device__ __forceinline__ float lrelu_f(float v) { return v >= 0.f ? v : 0.2f * v; }

// =============== generic tiled GEMM: C[M,N] = A[M,K] @ W[N,K]^T + bias ===============
// epi: 0 none, 1 gelu(exact), 2 lrelu then eval-BN (scale bng, shift bnb)
__global__ __launch_bounds__(256) void gemm_nt(
    const float* __restrict__ A, const float* __restrict__ W,
    const float* __restrict__ bias, float* __restrict__ C,
    int M, int N, int K, int epi,
    const float* __restrict__ bng, const float* __restrict__ bnb)
{
    __shared__ float As[16][65];
    __shared__ float Ws[16][65];
    const int bm = blockIdx.y, bn = blockIdx.x;
    const int tid = threadIdx.x;
    const int tx = tid & 15, ty = tid >> 4;
    float acc[4][4] = {{0.f}};
    const float* Ab = A + (size_t)bm * 64 * K;
    const float* Wb = W + (size_t)bn * 64 * K;
    for (int k0 = 0; k0 < K; k0 += 16) {
        #pragma unroll
        for (int i = 0; i < 4; i++) {
            int idx = tid + i * 256;
            int m = idx >> 4, kk = idx & 15;
            As[kk][m] = Ab[(size_t)m * K + k0 + kk];
            Ws[kk][m] = Wb[(size_t)m * K + k0 + kk];
        }
        __syncthreads();
        #pragma unroll
        for (int kk = 0; kk < 16; kk++) {
            float a[4], w[4];
            #pragma unroll
            for (int i = 0; i < 4; i++) a[i] = As[kk][ty * 4 + i];
            #pragma unroll
            for (int j = 0; j < 4; j++) w[j] = Ws[kk][tx * 4 + j];
            #pragma unroll
            for (int i = 0; i < 4; i++)
                #pragma unroll
                for (int j = 0; j < 4; j++)
                    acc[i][j] = fmaf(a[i], w[j], acc[i][j]);
        }
        __syncthreads();
    }
    #pragma unroll
    for (int i = 0; i < 4; i++) {
        int row = bm * 64 + ty * 4 + i;
        #pragma unroll
        for (int j = 0; j < 4; j++) {
            int col = bn * 64 + tx * 4 + j;
            float v = acc[i][j] + bias[col];
            if (epi == 1) {
                v = 0.5f * v * (1.0f + erff(v * 0.70710678118654752f));
            } else if (epi == 2) {
                v = lrelu_f(v);
                v = v * (bng[col] * BN_F) + bnb[col];
            }
            C[(size_t)row * N + col] = v;
        }
    }
}

// =============== encoder first conv (direct): x(B,T,DIN) -> out(B,128,768) btc ===============
__global__ __launch_bounds__(256) void conv0_enc(
    const float* __restrict__ x, const float* __restrict__ w, const float* __restrict__ b0,
    const float* __restrict__ g, const float* __restrict__ bb, float* __restrict__ out)
{
    int i = blockIdx.x * 256 + threadIdx.x;
    if (i >= BB * 128 * DD) return;
    int co = i % DD;
    int t  = (i / DD) % 128;
    int b  = i / (DD * 128);
    float acc = b0[co];
    const float* wp = w + (size_t)co * DIN * 5;
    #pragma unroll
    for (int k = 0; k < 5; k++) {
        int ti = 2 * t - 2 + k;
        ti = ti < 0 ? 0 : (ti > TT - 1 ? TT - 1 : ti);
        const float* xp = x + ((size_t)b * TT + ti) * DIN;
        for (int ci = 0; ci < DIN; ci++) acc = fmaf(xp[ci], wp[ci * 5 + k], acc);
    }
    acc = lrelu_f(acc);
    out[i] = acc * (g[co] * BN_F) + bb[co];
}

// =============== weight reorder: w[co][ci][k] -> wr[co][k*768+ci] ===============
__global__ __launch_bounds__(256) void reorder_w(const float* __restrict__ w, float* __restrict__ wr)
{
    int i = blockIdx.x * 256 + threadIdx.x;
    if (i >= DD * DD * 5) return;
    int k  = i % 5;
    int t  = i / 5;
    int ci = t % DD;
    int co = t / DD;
    wr[(size_t)co * (5 * DD) + k * DD + ci] = w[i];
}

// =============== im2col (stride1, pad2, replicate): x(B,T,768) -> xc(B*T, 5*768) ===============
__global__ __launch_bounds__(256) void im2col_rep(const float* __restrict__ x, float* __restrict__ xc, int T)
{
    size_t i = (size_t)blockIdx.x * 256 + threadIdx.x;
    size_t total = (size_t)BB * T * 5 * DD;
    if (i >= total) return;
    int c = (int)(i % DD);
    size_t t2 = i / DD;
    int k = (int)(t2 % 5);
    size_t t3 = t2 / 5;
    int t = (int)(t3 % T);
    int b = (int)(t3 / T);
    int ti = t - 2 + k;
    ti = ti < 0 ? 0 : (ti > T - 1 ? T - 1 : ti);
    xc[i] = x[((size_t)b * T + ti) * DD + c];
}

// =============== maxpool over time pairs, (B,2*To,768)->(B,To,768) ===============
__global__ __launch_bounds__(256) void maxpool2(const float* __restrict__ in, float* __restrict__ out, int To)
{
    int i = blockIdx.x * 256 + threadIdx.x;
    if (i >= BB * To * DD) return;
    int c = i % DD;
    int t = (i / DD) % To;
    int b = i / (DD * To);
    const float* p = in + ((size_t)b * 2 * To + 2 * t) * DD + c;
    out[i] = fmaxf(p[0], p[DD]);
}

// =============== repeat_interleave(2) over time, (B,Ti,768)->(B,2Ti,768) ===============
__global__ __launch_bounds__(256) void rep2(const float* __restrict__ in, float* __restrict__ out, int Ti)
{
    int i = blockIdx.x * 256 + threadIdx.x;
    if (i >= BB * 2 * Ti * DD) return;
    int c = i % DD;
    int t = (i / DD) % (2 * Ti);
    int b = i / (DD * 2 * Ti);
    out[i] = in[((size_t)b * Ti + (t >> 1)) * DD + c];
}

// =============== attention: scores = Q.K^T / 8 ===============
__global__ __launch_bounds__(256) void attn_scores(const float* __restrict__ qkv, float* __restrict__ sc, int S)
{
    int i = blockIdx.x * 256 + threadIdx.x;
    if (i >= BB * HH * S * S) return;
    int k = i % S;
    int t = i / S;
    int q = t % S; t /= S;
    int h = t % HH;
    int b = t / HH;
    const float* qp = qkv + ((size_t)(b * S + q)) * QKVD + h * DHD;
    const float* kp = qkv + ((size_t)(b * S + k)) * QKVD + DD + h * DHD;
    float s = 0.f;
    #pragma unroll
    for (int d = 0; d < DHD; d++) s = fmaf(qp[d], kp[d], s);
    sc[i] = s * 0.125f;
}

__global__ __launch_bounds__(256) void softmax_rows(float* __restrict__ sc, int S)
{
    int row = blockIdx.x;
    float* p = sc + (size_t)row * S;
    int tid = threadIdx.x;
    __shared__ float red[256];
    float m = -1e30f;
    for (int d = tid; d < S; d += 256) m = fmaxf(m, p[d]);
    red[tid] = m; __syncthreads();
    for (int s = 128; s > 0; s >>= 1) { if (tid < s) red[tid] = fmaxf(red[tid], red[tid + s]); __syncthreads(); }
    m = red[0]; __syncthreads();
    float sum = 0.f;
    for (int d = tid; d < S; d += 256) { float e = expf(p[d] - m); p[d] = e; sum += e; }
    red[tid] = sum; __syncthreads();
    for (int s = 128; s > 0; s >>= 1) { if (tid < s) red[tid] += red[tid + s]; __syncthreads(); }
    float inv = 1.0f / red[0];
    for (int d = tid; d < S; d += 256) p[d] *= inv;
}

__global__ __launch_bounds__(256) void attn_out(const float* __restrict__ sc, const float* __restrict__ qkv,
                                                float* __restrict__ o, int S)
{
    int i = blockIdx.x * 256 + threadIdx.x;
    if (i >= BB * S * DD) return;
    int j = i % DD;
    int t = i / DD;
    int q = t % S;
    int b = t / S;
    int h = j >> 6;
    const float* p = sc + (((size_t)(b * HH + h) * S + q)) * S;
    const float* vp = qkv + 2 * DD + j + (size_t)b * S * QKVD;
    float s = 0.f;
    for (int k = 0; k < S; k++) s = fmaf(p[k], vp[(size_t)k * QKVD], s);
    o[(size_t)(b * S + q) * DD + j] = s;
}

// =============== x = LN(x + y) * g + b, in place on x; one block per row of 768 ===============
__global__ __launch_bounds__(256) void add_ln(float* __restrict__ x, const float* __restrict__ y,
                                              const float* __restrict__ g, const float* __restrict__ bb)
{
    int row = blockIdx.x;
    int tid = threadIdx.x;
    __shared__ float buf[DD];
    __shared__ float red[256];
    float* xp = x + (size_t)row * DD;
    const float* yp = y + (size_t)row * DD;
    float s = 0.f;
    for (int d = tid; d < DD; d += 256) { float v = xp[d] + yp[d]; buf[d] = v; s += v; }
    red[tid] = s; __syncthreads();
    for (int k = 128; k > 0; k >>= 1) { if (tid < k) red[tid] += red[tid + k]; __syncthreads(); }
    float mean = red[0] * (1.0f / DD);
    __syncthreads();
    float s2 = 0.f;
    for (int d = tid; d < DD; d += 256) { float v = buf[d] - mean; s2 += v * v; }
    red[tid] = s2; __syncthreads();
    for (int k = 128; k > 0; k >>= 1) { if (tid < k) red[tid] += red[tid + k]; __syncthreads(); }
    float rstd = rsqrtf(red[0] * (1.0f / DD) + 1e-5f);
    for (int d = tid; d < DD; d += 256) xp[d] = (buf[d] - mean) * rstd * g[d] + bb[d];
}

// =============== VQ argmin: one block per row ===============
__global__ __launch_bounds__(256) void vq_argmin(const float* __restrict__ h, const float* __restrict__ cb,
                                                 int* __restrict__ idx_out, float* __restrict__ idx_f)
{
    int row = blockIdx.x;
    int tid = threadIdx.x;
    __shared__ float z[DD];
    const float* hp = h + (size_t)row * DD;
    for (int d = tid; d < DD; d += 256) z[d] = hp[d];
    __syncthreads();
    float best = 3.4e38f;
    int bi = 0x7fffffff;
    for (int c = tid; c < KK; c += 256) {
        const float* e = cb + (size_t)c * DD;
        float acc = 0.f;
        for (int d = 0; d < DD; d++) { float ev = e[d]; acc = fmaf(ev, ev - 2.f * z[d], acc); }
        if (acc < best) { best = acc; bi = c; }
    }
    __shared__ float bred[256];
    __shared__ int   ired[256];
    bred[tid] = best; ired[tid] = bi; __syncthreads();
    for (int s = 128; s > 0; s >>= 1) {
        if (tid < s) {
            float o = bred[tid + s]; int oi = ired[tid + s];
            if (o < bred[tid] || (o == bred[tid] && oi < ired[tid])) { bred[tid] = o; ired[tid] = oi; }
        }
        __syncthreads();
    }
    if (tid == 0) { idx_out[row] = ired[0]; idx_f[row] = (float)ired[0]; }
}

// =============== zq gather + VQ loss ===============
__global__ __launch_bounds__(256) void zq_loss(const float* __restrict__ cb, const int* __restrict__ idx,
                                               const float* __restrict__ h, float* __restrict__ zq,
                                               float* __restrict__ loss)
{
    int i = blockIdx.x * 256 + threadIdx.x;
    float d2 = 0.f;
    if (i < 256 * DD) {
        int r = i / DD, d = i % DD;
        float q = cb[(size_t)idx[r] * DD + d];
        zq[i] = q;
        float df = q - h[i];
        d2 = df * df;
    }
    __shared__ float red[256];
    red[threadIdx.x] = d2; __syncthreads();
    for (int s = 128; s > 0; s >>= 1) { if (threadIdx.x < s) red[threadIdx.x] += red[threadIdx.x + s]; __syncthreads(); }
    if (threadIdx.x == 0) atomicAdd(loss, red[0] * (1.25f / (256.0f * (float)DD)));
}

// =============== decoder ConvTranspose1d (direct): zq(B,32,768) -> out(B,64,768), lrelu+bn ===============
__global__ __launch_bounds__(256) void convT_dec(
    const float* __restrict__ zq, const float* __restrict__ wt, const float* __restrict__ b0,
    const float* __restrict__ g, const float* __restrict__ bb, float* __restrict__ out)
{
    int i = blockIdx.x * 256 + threadIdx.x;
    if (i >= BB * 64 * DD) return;
    int co = i % DD;
    int t  = (i / DD) % 64;
    int b  = i / (DD * 64);
    float acc = b0[co];
    int smin = (t >= 2) ? ((t - 1) >> 1) : 0;      // ceil((t-2)/2)
    int smax = (t + 2) >> 1; if (smax > 31) smax = 31;
    for (int s = smin; s <= smax; s++) {
        int k = t + 2 - 2 * s;
        const float* xp = zq + ((size_t)b * 32 + s) * DD;
        const float* wp = wt + (size_t)co * 5 + k;   // wt[ci][co][k] : ci stride 768*5
        for (int ci = 0; ci < DD; ci++) acc = fmaf(xp[ci], wp[(size_t)ci * (DD * 5)], acc);
    }
    acc = lrelu_f(acc);
    out[i] = acc * (g[co] * BN_F) + bb[co];
}

// =============== final cross conv (zero pad): y(B,256,768) -> out(B,256,53) ===============
__global__ __launch_bounds__(256) void cross_conv(const float* __restrict__ y, const float* __restrict__ w,
                                                  const float* __restrict__ b0, float* __restrict__ out)
{
    int i = blockIdx.x * 256 + threadIdx.x;
    if (i >= BB * TT * DIN) return;
    int co = i % DIN;
    int t  = (i / DIN) % TT;
    int b  = i / (DIN * TT);
    float acc = b0[co];
    const float* wp = w + (size_t)co * DD * 5;
    #pragma unroll
    for (int k = 0; k < 5; k++) {
        int ti = t - 2 + k;
        if (ti < 0 || ti >= TT) continue;
        const float* yp = y + ((size_t)b * TT + ti) * DD;
        for (int ci = 0; ci < DD; ci++) acc = fmaf(yp[ci], wp[ci * 5 + k], acc);
    }
    out[i] = acc;
}

// ================= host orchestration =================
static void run_tlayer(float* X, float* qkv, float* sc, float* attno, float* proj, float* ff,
                       const float* in_w, const float* in_b, const float* out_w, const float* out_b,
                       const float* g1, const float* b1, const float* f1w, const float* f1b,
                       const float* f2w, const float* f2b, const float* g2, const float* b2,
                       int S, hipStream_t stream)
{
    int M = BB * S;
    gemm_nt<<<dim3(QKVD / 64, M / 64), 256, 0, stream>>>(X, in_w, in_b, qkv, M, QKVD, DD, 0, nullptr, nullptr);
    attn_scores<<<(BB * HH * S * S + 255) / 256, 256, 0, stream>>>(qkv, sc, S);
    softmax_rows<<<BB * HH * S, 256, 0, stream>>>(sc, S);
    attn_out<<<(M * DD + 255) / 256, 256, 0, stream>>>(sc, qkv, attno, S);
    gemm_nt<<<dim3(DD / 64, M / 64), 256, 0, stream>>>(attno, out_w, out_b, proj, M, DD, DD, 0, nullptr, nullptr);
    add_ln<<<M, 256, 0, stream>>>(X, proj, g1, b1);
    gemm_nt<<<dim3(FF_ / 64, M / 64), 256, 0, stream>>>(X, f1w, f1b, ff, M, FF_, DD, 1, nullptr, nullptr);
    gemm_nt<<<dim3(DD / 64, M / 64), 256, 0, stream>>>(ff, f2w, f2b, proj, M, DD, FF_, 0, nullptr, nullptr);
    add_ln<<<M, 256, 0, stream>>>(X, proj, g2, b2);
}

extern "C" void kernel_launch(void* const* d_in, const int* in_sizes, int n_in,
                              void* d_out, int out_size, void* d_ws, size_t ws_size,
                              hipStream_t stream)
{
    const float* P[48];
    for (int i = 0; i < 48 && i < n_in; i++) P[i] = (const float*)d_in[i];

    // Resolve input ordering ambiguity (setup_inputs dict order vs reference signature order).
    // dict order:     index 24 = dec_in_w (4*2304*768 = 7,077,888)
    // signature order:index 24 = dec_ct_w (768*768*5 = 2,949,120)
    int i_dec_in_w, i_dec_in_b, i_dec_out_w, i_dec_out_b, i_dec_ln1_g, i_dec_ln1_b;
    int i_dec_ff1_w, i_dec_ff1_b, i_dec_ff2_w, i_dec_ff2_b, i_dec_ln2_g, i_dec_ln2_b;
    int i_dec_ct_w, i_dec_ct_b, i_dec_bn0_g, i_dec_bn0_b, i_dec_cw, i_dec_cb, i_dec_bn_g, i_dec_bn_b;
    int i_dec_lin_w, i_dec_lin_b;
    if (in_sizes[24] == DD * DD * 5) { // signature order
        i_dec_ct_w = 24; i_dec_ct_b = 25; i_dec_bn0_g = 26; i_dec_bn0_b = 27;
        i_dec_cw = 28; i_dec_cb = 29; i_dec_bn_g = 30; i_dec_bn_b = 31;
        i_dec_lin_w = 32; i_dec_lin_b = 33;
        i_dec_in_w = 34; i_dec_in_b = 35; i_dec_out_w = 36; i_dec_out_b = 37;
        i_dec_ln1_g = 38; i_dec_ln1_b = 39; i_dec_ff1_w = 40; i_dec_ff1_b = 41;
        i_dec_ff2_w = 42; i_dec_ff2_b = 43; i_dec_ln2_g = 44; i_dec_ln2_b = 45;
    } else { // dict order
        i_dec_in_w = 24; i_dec_in_b = 25; i_dec_out_w = 26; i_dec_out_b = 27;
        i_dec_ln1_g = 28; i_dec_ln1_b = 29; i_dec_ff1_w = 30; i_dec_ff1_b = 31;
        i_dec_ff2_w = 32; i_dec_ff2_b = 33; i_dec_ln2_g = 34; i_dec_ln2_b = 35;
        i_dec_ct_w = 36; i_dec_ct_b = 37; i_dec_bn0_g = 38; i_dec_bn0_b = 39;
        i_dec_cw = 40; i_dec_cb = 41; i_dec_bn_g = 42; i_dec_bn_b = 43;
        i_dec_lin_w = 44; i_dec_lin_b = 45;
    }
    const int i_cross_w = 46, i_cross_b = 47;

    // workspace layout (floats)
    float* ws    = (float*)d_ws;
    float* bufA  = ws + 0;          // 1,572,864
    float* bufB  = ws + 1572864;    // 1,572,864
    float* X     = ws + 3145728;    // 1,572,864
    float* attno = ws + 4718592;    // 1,572,864
    float* proj  = ws + 6291456;    // 1,572,864
    float* qkv   = ws + 7864320;    // 4,718,592  (aliases im2col)
    float* sc    = ws + 12582912;   // 6,291,456  (aliases ff)
    float* wr    = ws + 18874368;   // 2,949,120
    int*   idxb  = (int*)(ws + 21823488); // 256
    float* out   = (float*)d_out;
    float* lossp = out + BB * TT * DIN;        // 108544
    float* idxf  = out + BB * TT * DIN + 1;    // 108545

    hipMemsetAsync(lossp, 0, sizeof(float), stream);

    // ---------------- encoder squasher ----------------
    conv0_enc<<<(BB * 128 * DD + 255) / 256, 256, 0, stream>>>(P[0], P[2], P[3], P[4], P[5], bufA);
    int T = 128;
    for (int i = 0; i < 2; i++) {
        reorder_w<<<(DD * DD * 5 + 255) / 256, 256, 0, stream>>>(P[6] + (size_t)i * DD * DD * 5, wr);
        im2col_rep<<<(int)(((size_t)BB * T * 5 * DD + 255) / 256), 256, 0, stream>>>(bufA, qkv, T);
        gemm_nt<<<dim3(DD / 64, BB * T / 64), 256, 0, stream>>>(qkv, wr, P[7] + i * DD, bufB,
                                                                BB * T, DD, 5 * DD, 2, P[8] + i * DD, P[9] + i * DD);
        maxpool2<<<(BB * (T / 2) * DD + 255) / 256, 256, 0, stream>>>(bufB, bufA, T / 2);
        T /= 2;
    }
    // encoder linear (B*32, 768) -> X
    gemm_nt<<<dim3(DD / 64, 256 / 64), 256, 0, stream>>>(bufA, P[10], P[11], X, 256, DD, DD, 0, nullptr, nullptr);
    // encoder transformer, S=32
    for (int l = 0; l < LL; l++) {
        run_tlayer(X, qkv, sc, attno, proj, sc,
                   P[12] + (size_t)l * QKVD * DD, P[13] + (size_t)l * QKVD,
                   P[14] + (size_t)l * DD * DD,  P[15] + (size_t)l * DD,
                   P[16] + (size_t)l * DD,       P[17] + (size_t)l * DD,
                   P[18] + (size_t)l * FF_ * DD, P[19] + (size_t)l * FF_,
                   P[20] + (size_t)l * DD * FF_, P[21] + (size_t)l * DD,
                   P[22] + (size_t)l * DD,       P[23] + (size_t)l * DD,
                   32, stream);
    }
    // ---------------- VQ ----------------
    vq_argmin<<<256, 256, 0, stream>>>(X, P[1], idxb, idxf);
    zq_loss<<<(256 * DD + 255) / 256, 256, 0, stream>>>(P[1], idxb, X, bufA, lossp);
    // ---------------- decoder expander ----------------
    convT_dec<<<(BB * 64 * DD + 255) / 256, 256, 0, stream>>>(bufA, P[i_dec_ct_w], P[i_dec_ct_b],
                                                              P[i_dec_bn0_g], P[i_dec_bn0_b], bufB);
    T = 64;
    for (int i = 0; i < 2; i++) {
        reorder_w<<<(DD * DD * 5 + 255) / 256, 256, 0, stream>>>(P[i_dec_cw] + (size_t)i * DD * DD * 5, wr);
        im2col_rep<<<(int)(((size_t)BB * T * 5 * DD + 255) / 256), 256, 0, stream>>>(bufB, qkv, T);
        gemm_nt<<<dim3(DD / 64, BB * T / 64), 256, 0, stream>>>(qkv, wr, P[i_dec_cb] + i * DD, bufA,
                                                                BB * T, DD, 5 * DD, 2,
                                                                P[i_dec_bn_g] + i * DD, P[i_dec_bn_b] + i * DD);
        rep2<<<(BB * 2 * T * DD + 255) / 256, 256, 0, stream>>>(bufA, bufB, T);
        T *= 2;
    }
    // decoder linear (B*256, 768) -> X
    gemm_nt<<<dim3(DD / 64, 2048 / 64), 256, 0, stream>>>(bufB, P[i_dec_lin_w], P[i_dec_lin_b], X,
                                                          2048, DD, DD, 0, nullptr, nullptr);
    // decoder transformer, S=256
    for (int l = 0; l < LL; l++) {
        run_tlayer(X, qkv, sc, attno, proj, sc,
                   P[i_dec_in_w]  + (size_t)l * QKVD * DD, P[i_dec_in_b]  + (size_t)l * QKVD,
                   P[i_dec_out_w] + (size_t)l * DD * DD,   P[i_dec_out_b] + (size_t)l * DD,
                   P[i_dec_ln1_g] + (size_t)l * DD,        P[i_dec_ln1_b] + (size_t)l * DD,
                   P[i_dec_ff1_w] + (size_t)l * FF_ * DD,  P[i_dec_ff1_b] + (size_t)l * FF_,
                   P[i_dec_ff2_w] + (size_t)l * DD * FF_,  P[i_dec_ff2_b] + (size_t)l * DD,
                   P[i_dec_ln2_g] + (size_t)l * DD,        P[i_dec_ln2_b] + (size_t)l * DD,
                   256, stream);
    }
    // final cross conv -> d_out
    cross_conv<<<(BB * TT * DIN + 255) / 256, 256, 0, stream>>>(X, P[i_cross_w], P[i_cross_b], out);
}

// Round 2
// 6381.707 us; speedup vs baseline: 1.6624x; 1.6624x over previous
//
#include <hip/hip_runtime.h>
#include <hip/hip_bf16.h>

// ---- model dims ----
#define BB   8
#define TT   256
#define DIN  53
#define DD   768
#define HH   12
#define DHD  64
#define FF_  3072
#define LL   4
#define KK   1024
#define QKVD 2304
#define BN_F 0.9999950000374997f  // 1/sqrt(1+1e-5)

__device__ __forceinline__ float lrelu_f(float v) { return v >= 0.f ? v : 0.2f * v; }

// =============== generic tiled GEMM: C[M,N] = A[M,K] @ W[N,K]^T + bias ===============
// epi: 0 none, 1 gelu(exact), 2 lrelu then eval-BN (scale bng, shift bnb)
// C row written at (row*row_scale + row_off)
__global__ __launch_bounds__(256) void gemm_nt(
    const float* __restrict__ A, const float* __restrict__ W,
    const float* __restrict__ bias, float* __restrict__ C,
    int M, int N, int K, int epi,
    const float* __restrict__ bng, const float* __restrict__ bnb,
    int row_scale, int row_off)
{
    __shared__ float As[16][68];
    __shared__ float Ws[16][68];
    const int bm = blockIdx.y, bn = blockIdx.x;
    const int tid = threadIdx.x;
    const int tx = tid & 15, ty = tid >> 4;
    float acc[4][4] = {{0.f}};
    const float* Ab = A + (size_t)bm * 64 * K;
    const float* Wb = W + (size_t)bn * 64 * K;
    for (int k0 = 0; k0 < K; k0 += 16) {
        #pragma unroll
        for (int i = 0; i < 4; i++) {
            int idx = tid + i * 256;
            int m = idx >> 4, kk = idx & 15;
            As[kk][m] = Ab[(size_t)m * K + k0 + kk];
            Ws[kk][m] = Wb[(size_t)m * K + k0 + kk];
        }
        __syncthreads();
        #pragma unroll
        for (int kk = 0; kk < 16; kk++) {
            float a[4], w[4];
            #pragma unroll
            for (int i = 0; i < 4; i++) a[i] = As[kk][ty * 4 + i];
            #pragma unroll
            for (int j = 0; j < 4; j++) w[j] = Ws[kk][tx * 4 + j];
            #pragma unroll
            for (int i = 0; i < 4; i++)
                #pragma unroll
                for (int j = 0; j < 4; j++)
                    acc[i][j] = fmaf(a[i], w[j], acc[i][j]);
        }
        __syncthreads();
    }
    #pragma unroll
    for (int i = 0; i < 4; i++) {
        int row = bm * 64 + ty * 4 + i;
        #pragma unroll
        for (int j = 0; j < 4; j++) {
            int col = bn * 64 + tx * 4 + j;
            float v = acc[i][j] + bias[col];
            if (epi == 1) {
                v = 0.5f * v * (1.0f + erff(v * 0.70710678118654752f));
            } else if (epi == 2) {
                v = lrelu_f(v);
                v = v * (bng[col] * BN_F) + bnb[col];
            }
            C[(size_t)(row * row_scale + row_off) * N + col] = v;
        }
    }
}

// =============== encoder first conv (direct): x(B,T,DIN) -> out(B,128,768) btc ===============
__global__ __launch_bounds__(256) void conv0_enc(
    const float* __restrict__ x, const float* __restrict__ w, const float* __restrict__ b0,
    const float* __restrict__ g, const float* __restrict__ bb, float* __restrict__ out)
{
    int i = blockIdx.x * 256 + threadIdx.x;
    if (i >= BB * 128 * DD) return;
    int co = i % DD;
    int t  = (i / DD) % 128;
    int b  = i / (DD * 128);
    float acc = b0[co];
    const float* wp = w + (size_t)co * DIN * 5;
    #pragma unroll
    for (int k = 0; k < 5; k++) {
        int ti = 2 * t - 2 + k;
        ti = ti < 0 ? 0 : (ti > TT - 1 ? TT - 1 : ti);
        const float* xp = x + ((size_t)b * TT + ti) * DIN;
        for (int ci = 0; ci < DIN; ci++) acc = fmaf(xp[ci], wp[ci * 5 + k], acc);
    }
    acc = lrelu_f(acc);
    out[i] = acc * (g[co] * BN_F) + bb[co];
}

// =============== weight reorder: w[co][ci][k] -> wr[co][k*768+ci] (mid convs) ===============
__global__ __launch_bounds__(256) void reorder_w(const float* __restrict__ w, float* __restrict__ wr)
{
    int i = blockIdx.x * 256 + threadIdx.x;
    if (i >= DD * DD * 5) return;
    int k  = i % 5;
    int t  = i / 5;
    int ci = t % DD;
    int co = t / DD;
    wr[(size_t)co * (5 * DD) + k * DD + ci] = w[i];
}

// =============== im2col (stride1, pad2, replicate): x(B,T,768) -> xc(B*T, 5*768) ===============
__global__ __launch_bounds__(256) void im2col_rep(const float* __restrict__ x, float* __restrict__ xc, int T)
{
    size_t i = (size_t)blockIdx.x * 256 + threadIdx.x;
    size_t total = (size_t)BB * T * 5 * DD;
    if (i >= total) return;
    int c = (int)(i % DD);
    size_t t2 = i / DD;
    int k = (int)(t2 % 5);
    size_t t3 = t2 / 5;
    int t = (int)(t3 % T);
    int b = (int)(t3 / T);
    int ti = t - 2 + k;
    ti = ti < 0 ? 0 : (ti > T - 1 ? T - 1 : ti);
    xc[i] = x[((size_t)b * T + ti) * DD + c];
}

// =============== maxpool over time pairs ===============
__global__ __launch_bounds__(256) void maxpool2(const float* __restrict__ in, float* __restrict__ out, int To)
{
    int i = blockIdx.x * 256 + threadIdx.x;
    if (i >= BB * To * DD) return;
    int c = i % DD;
    int t = (i / DD) % To;
    int b = i / (DD * To);
    const float* p = in + ((size_t)b * 2 * To + 2 * t) * DD + c;
    out[i] = fmaxf(p[0], p[DD]);
}

// =============== repeat_interleave(2) over time ===============
__global__ __launch_bounds__(256) void rep2(const float* __restrict__ in, float* __restrict__ out, int Ti)
{
    int i = blockIdx.x * 256 + threadIdx.x;
    if (i >= BB * 2 * Ti * DD) return;
    int c = i % DD;
    int t = (i / DD) % (2 * Ti);
    int b = i / (DD * 2 * Ti);
    out[i] = in[((size_t)b * Ti + (t >> 1)) * DD + c];
}

// =============== attention naive (S=32 only) ===============
__global__ __launch_bounds__(256) void attn_scores(const float* __restrict__ qkv, float* __restrict__ sc, int S)
{
    int i = blockIdx.x * 256 + threadIdx.x;
    if (i >= BB * HH * S * S) return;
    int k = i % S;
    int t = i / S;
    int q = t % S; t /= S;
    int h = t % HH;
    int b = t / HH;
    const float* qp = qkv + ((size_t)(b * S + q)) * QKVD + h * DHD;
    const float* kp = qkv + ((size_t)(b * S + k)) * QKVD + DD + h * DHD;
    float s = 0.f;
    #pragma unroll
    for (int d = 0; d < DHD; d++) s = fmaf(qp[d], kp[d], s);
    sc[i] = s * 0.125f;
}

__global__ __launch_bounds__(256) void attn_out(const float* __restrict__ sc, const float* __restrict__ qkv,
                                                float* __restrict__ o, int S)
{
    int i = blockIdx.x * 256 + threadIdx.x;
    if (i >= BB * S * DD) return;
    int j = i % DD;
    int t = i / DD;
    int q = t % S;
    int b = t / S;
    int h = j >> 6;
    const float* p = sc + (((size_t)(b * HH + h) * S + q)) * S;
    const float* vp = qkv + 2 * DD + j + (size_t)b * S * QKVD;
    float s = 0.f;
    for (int k = 0; k < S; k++) s = fmaf(p[k], vp[(size_t)k * QKVD], s);
    o[(size_t)(b * S + q) * DD + j] = s;
}

// =============== batched scores GEMM (S=256): sc[bh] = Q_bh @ K_bh^T / 8 ===============
__global__ __launch_bounds__(256) void attn_scores_gemm(const float* __restrict__ qkv, float* __restrict__ sc)
{
    const int S = 256;
    int bh = blockIdx.z;
    int b = bh / HH, h = bh % HH;
    const float* Qb = qkv + (size_t)b * S * QKVD + h * DHD;
    const float* Kb = qkv + (size_t)b * S * QKVD + DD + h * DHD;
    __shared__ float As[64][65];
    __shared__ float Ws[64][65];
    int tid = threadIdx.x;
    int tx = tid & 15, ty = tid >> 4;
    #pragma unroll
    for (int i = 0; i < 16; i++) {
        int idx = tid + i * 256;
        int m = idx >> 6, kk = idx & 63;
        As[m][kk] = Qb[(size_t)(blockIdx.y * 64 + m) * QKVD + kk];
        Ws[m][kk] = Kb[(size_t)(blockIdx.x * 64 + m) * QKVD + kk];
    }
    __syncthreads();
    float acc[4][4] = {{0.f}};
    #pragma unroll 4
    for (int kk = 0; kk < 64; kk++) {
        float a[4], w[4];
        #pragma unroll
        for (int i = 0; i < 4; i++) a[i] = As[ty * 4 + i][kk];
        #pragma unroll
        for (int j = 0; j < 4; j++) w[j] = Ws[tx * 4 + j][kk];
        #pragma unroll
        for (int i = 0; i < 4; i++)
            #pragma unroll
            for (int j = 0; j < 4; j++)
                acc[i][j] = fmaf(a[i], w[j], acc[i][j]);
    }
    #pragma unroll
    for (int i = 0; i < 4; i++) {
        int q = blockIdx.y * 64 + ty * 4 + i;
        #pragma unroll
        for (int j = 0; j < 4; j++) {
            int k = blockIdx.x * 64 + tx * 4 + j;
            sc[((size_t)bh * S + q) * S + k] = acc[i][j] * 0.125f;
        }
    }
}

// =============== batched AV GEMM (S=256): attno[b,q, h*64+n] = P_bh @ V_bh ===============
__global__ __launch_bounds__(256) void attn_av_gemm(const float* __restrict__ sc, const float* __restrict__ qkv,
                                                    float* __restrict__ o)
{
    const int S = 256;
    int bh = blockIdx.z;
    int b = bh / HH, h = bh % HH;
    const float* Vb = qkv + (size_t)b * S * QKVD + 2 * DD + h * DHD;
    const float* Ab = sc + (size_t)bh * S * S + (size_t)blockIdx.y * 64 * S;
    __shared__ float As[64][65];
    __shared__ float Bs[64][65];
    int tid = threadIdx.x;
    int tx = tid & 15, ty = tid >> 4;
    float acc[4][4] = {{0.f}};
    for (int k0 = 0; k0 < S; k0 += 64) {
        #pragma unroll
        for (int i = 0; i < 16; i++) {
            int idx = tid + i * 256;
            int m = idx >> 6, kk = idx & 63;
            As[m][kk] = Ab[(size_t)m * S + k0 + kk];
            Bs[m][kk] = Vb[(size_t)(k0 + m) * QKVD + kk];  // Bs[kk_local=m][n=kk]
        }
        __syncthreads();
        #pragma unroll 4
        for (int kk = 0; kk < 64; kk++) {
            float a[4], w[4];
            #pragma unroll
            for (int i = 0; i < 4; i++) a[i] = As[ty * 4 + i][kk];
            #pragma unroll
            for (int j = 0; j < 4; j++) w[j] = Bs[kk][tx * 4 + j];
            #pragma unroll
            for (int i = 0; i < 4; i++)
                #pragma unroll
                for (int j = 0; j < 4; j++)
                    acc[i][j] = fmaf(a[i], w[j], acc[i][j]);
        }
        __syncthreads();
    }
    #pragma unroll
    for (int i = 0; i < 4; i++) {
        int q = blockIdx.y * 64 + ty * 4 + i;
        #pragma unroll
        for (int j = 0; j < 4; j++) {
            int n = tx * 4 + j;
            o[((size_t)b * S + q) * DD + h * DHD + n] = acc[i][j];
        }
    }
}

__global__ __launch_bounds__(256) void softmax_rows(float* __restrict__ sc, int S)
{
    int row = blockIdx.x;
    float* p = sc + (size_t)row * S;
    int tid = threadIdx.x;
    __shared__ float red[256];
    float m = -1e30f;
    for (int d = tid; d < S; d += 256) m = fmaxf(m, p[d]);
    red[tid] = m; __syncthreads();
    for (int s = 128; s > 0; s >>= 1) { if (tid < s) red[tid] = fmaxf(red[tid], red[tid + s]); __syncthreads(); }
    m = red[0]; __syncthreads();
    float sum = 0.f;
    for (int d = tid; d < S; d += 256) { float e = expf(p[d] - m); p[d] = e; sum += e; }
    red[tid] = sum; __syncthreads();
    for (int s = 128; s > 0; s >>= 1) { if (tid < s) red[tid] += red[tid + s]; __syncthreads(); }
    float inv = 1.0f / red[0];
    for (int d = tid; d < S; d += 256) p[d] *= inv;
}

// =============== x = LN(x + y) * g + b, in place on x ===============
__global__ __launch_bounds__(256) void add_ln(float* __restrict__ x, const float* __restrict__ y,
                                              const float* __restrict__ g, const float* __restrict__ bb)
{
    int row = blockIdx.x;
    int tid = threadIdx.x;
    __shared__ float buf[DD];
    __shared__ float red[256];
    float* xp = x + (size_t)row * DD;
    const float* yp = y + (size_t)row * DD;
    float s = 0.f;
    for (int d = tid; d < DD; d += 256) { float v = xp[d] + yp[d]; buf[d] = v; s += v; }
    red[tid] = s; __syncthreads();
    for (int k = 128; k > 0; k >>= 1) { if (tid < k) red[tid] += red[tid + k]; __syncthreads(); }
    float mean = red[0] * (1.0f / DD);
    __syncthreads();
    float s2 = 0.f;
    for (int d = tid; d < DD; d += 256) { float v = buf[d] - mean; s2 += v * v; }
    red[tid] = s2; __syncthreads();
    for (int k = 128; k > 0; k >>= 1) { if (tid < k) red[tid] += red[tid + k]; __syncthreads(); }
    float rstd = rsqrtf(red[0] * (1.0f / DD) + 1e-5f);
    for (int d = tid; d < DD; d += 256) xp[d] = (buf[d] - mean) * rstd * g[d] + bb[d];
}

// =============== VQ argmin ===============
__global__ __launch_bounds__(256) void vq_argmin(const float* __restrict__ h, const float* __restrict__ cb,
                                                 int* __restrict__ idx_out, float* __restrict__ idx_f)
{
    int row = blockIdx.x;
    int tid = threadIdx.x;
    __shared__ float z[DD];
    const float* hp = h + (size_t)row * DD;
    for (int d = tid; d < DD; d += 256) z[d] = hp[d];
    __syncthreads();
    float best = 3.4e38f;
    int bi = 0x7fffffff;
    for (int c = tid; c < KK; c += 256) {
        const float* e = cb + (size_t)c * DD;
        float acc = 0.f;
        for (int d = 0; d < DD; d++) { float ev = e[d]; acc = fmaf(ev, ev - 2.f * z[d], acc); }
        if (acc < best) { best = acc; bi = c; }
    }
    __shared__ float bred[256];
    __shared__ int   ired[256];
    bred[tid] = best; ired[tid] = bi; __syncthreads();
    for (int s = 128; s > 0; s >>= 1) {
        if (tid < s) {
            float o = bred[tid + s]; int oi = ired[tid + s];
            if (o < bred[tid] || (o == bred[tid] && oi < ired[tid])) { bred[tid] = o; ired[tid] = oi; }
        }
        __syncthreads();
    }
    if (tid == 0) { idx_out[row] = ired[0]; idx_f[row] = (float)ired[0]; }
}

// =============== zq gather + VQ loss ===============
__global__ __launch_bounds__(256) void zq_loss(const float* __restrict__ cb, const int* __restrict__ idx,
                                               const float* __restrict__ h, float* __restrict__ zq,
                                               float* __restrict__ loss)
{
    int i = blockIdx.x * 256 + threadIdx.x;
    float d2 = 0.f;
    if (i < 256 * DD) {
        int r = i / DD, d = i % DD;
        float q = cb[(size_t)idx[r] * DD + d];
        zq[i] = q;
        float df = q - h[i];
        d2 = df * df;
    }
    __shared__ float red[256];
    red[threadIdx.x] = d2; __syncthreads();
    for (int s = 128; s > 0; s >>= 1) { if (threadIdx.x < s) red[threadIdx.x] += red[threadIdx.x + s]; __syncthreads(); }
    if (threadIdx.x == 0) atomicAdd(loss, red[0] * (1.25f / (256.0f * (float)DD)));
}

// =============== convT weight reorder: wt[ci][co][k] -> We[co][j*768+ci] (k=2j), Wo (k=2j+1) ===============
__global__ __launch_bounds__(256) void reorder_ctw(const float* __restrict__ wt, float* __restrict__ We,
                                                   float* __restrict__ Wo)
{
    int i = blockIdx.x * 256 + threadIdx.x;
    if (i >= DD * DD * 5) return;
    int k  = i % 5;
    int co = (i / 5) % DD;
    int ci = i / (5 * DD);
    float v = wt[i];
    if ((k & 1) == 0) We[(size_t)co * (3 * DD) + (k >> 1) * DD + ci] = v;
    else             Wo[(size_t)co * (2 * DD) + (k >> 1) * DD + ci] = v;
}

// =============== convT im2col: zq(B,32,768) -> Ae(256, 2304), Ao(256, 1536), zero-padded ===============
__global__ __launch_bounds__(256) void im2colT(const float* __restrict__ zq, float* __restrict__ Ae,
                                               float* __restrict__ Ao)
{
    int i = blockIdx.x * 256 + threadIdx.x;
    const int TE = 256 * 3 * DD;
    const int TO = 256 * 2 * DD;
    if (i < TE) {
        int r = i / (3 * DD), c = i % (3 * DD);
        int j = c / DD, ci = c % DD;
        int b = r >> 5, u = r & 31;
        int s = u + 1 - j;
        Ae[i] = (s >= 0 && s < 32) ? zq[((size_t)(b * 32 + s)) * DD + ci] : 0.f;
    } else if (i < TE + TO) {
        int i2 = i - TE;
        int r = i2 / (2 * DD), c = i2 % (2 * DD);
        int j = c / DD, ci = c % DD;
        int b = r >> 5, u = r & 31;
        int s = u + 1 - j;
        Ao[i2] = (s >= 0 && s < 32) ? zq[((size_t)(b * 32 + s)) * DD + ci] : 0.f;
    }
}

// =============== cross weight reorder: w[co][ci][k] -> wcr[co][k*768+ci] ===============
__global__ __launch_bounds__(256) void reorder_crossw(const float* __restrict__ w, float* __restrict__ wcr)
{
    int i = blockIdx.x * 256 + threadIdx.x;
    if (i >= DIN * DD * 5) return;
    int k  = i % 5;
    int ci = (i / 5) % DD;
    int co = i / (5 * DD);
    wcr[(size_t)co * (5 * DD) + k * DD + ci] = w[i];
}

// =============== cross conv: one wave per output, lanes over K=3840 ===============
__global__ __launch_bounds__(256) void cross_conv_wave(const float* __restrict__ y, const float* __restrict__ wcr,
                                                       const float* __restrict__ b0, float* __restrict__ out)
{
    int gwid = (blockIdx.x * 256 + threadIdx.x) >> 6;   // global wave id = output index
    int lane = threadIdx.x & 63;
    if (gwid >= BB * TT * DIN) return;
    int co = gwid % DIN;
    int t  = (gwid / DIN) % TT;
    int b  = gwid / (DIN * TT);
    const float* wp = wcr + (size_t)co * (5 * DD);
    const float* yb = y + (size_t)b * TT * DD;
    float acc = 0.f;
    int ci = lane, k = 0;
    #pragma unroll 4
    for (int j = 0; j < 60; j++) {
        int ti = t - 2 + k;
        if (ti >= 0 && ti < TT)
            acc = fmaf(yb[(size_t)ti * DD + ci], wp[lane + 64 * j], acc);
        ci += 64;
        if (ci >= DD) { ci -= DD; k++; }
    }
    #pragma unroll
    for (int off = 32; off > 0; off >>= 1) acc += __shfl_down(acc, off);
    if (lane == 0) out[gwid] = acc + b0[co];
}

// ================= host orchestration =================
static void run_tlayer(float* X, float* qkv, float* sc, float* attno, float* proj,
                       const float* in_w, const float* in_b, const float* out_w, const float* out_b,
                       const float* g1, const float* b1, const float* f1w, const float* f1b,
                       const float* f2w, const float* f2b, const float* g2, const float* b2,
                       int S, hipStream_t stream)
{
    int M = BB * S;
    gemm_nt<<<dim3(QKVD / 64, M / 64), 256, 0, stream>>>(X, in_w, in_b, qkv, M, QKVD, DD, 0, nullptr, nullptr, 1, 0);
    if (S == 256) {
        attn_scores_gemm<<<dim3(4, 4, BB * HH), 256, 0, stream>>>(qkv, sc);
        softmax_rows<<<BB * HH * S, 256, 0, stream>>>(sc, S);
        attn_av_gemm<<<dim3(1, 4, BB * HH), 256, 0, stream>>>(sc, qkv, attno);
    } else {
        attn_scores<<<(BB * HH * S * S + 255) / 256, 256, 0, stream>>>(qkv, sc, S);
        softmax_rows<<<BB * HH * S, 256, 0, stream>>>(sc, S);
        attn_out<<<(M * DD + 255) / 256, 256, 0, stream>>>(sc, qkv, attno, S);
    }
    gemm_nt<<<dim3(DD / 64, M / 64), 256, 0, stream>>>(attno, out_w, out_b, proj, M, DD, DD, 0, nullptr, nullptr, 1, 0);
    add_ln<<<M, 256, 0, stream>>>(X, proj, g1, b1);
    gemm_nt<<<dim3(FF_ / 64, M / 64), 256, 0, stream>>>(X, f1w, f1b, sc, M, FF_, DD, 1, nullptr, nullptr, 1, 0);
    gemm_nt<<<dim3(DD / 64, M / 64), 256, 0, stream>>>(sc, f2w, f2b, proj, M, DD, FF_, 0, nullptr, nullptr, 1, 0);
    add_ln<<<M, 256, 0, stream>>>(X, proj, g2, b2);
}

extern "C" void kernel_launch(void* const* d_in, const int* in_sizes, int n_in,
                              void* d_out, int out_size, void* d_ws, size_t ws_size,
                              hipStream_t stream)
{
    const float* P[48];
    for (int i = 0; i < 48 && i < n_in; i++) P[i] = (const float*)d_in[i];

    int i_dec_in_w, i_dec_in_b, i_dec_out_w, i_dec_out_b, i_dec_ln1_g, i_dec_ln1_b;
    int i_dec_ff1_w, i_dec_ff1_b, i_dec_ff2_w, i_dec_ff2_b, i_dec_ln2_g, i_dec_ln2_b;
    int i_dec_ct_w, i_dec_ct_b, i_dec_bn0_g, i_dec_bn0_b, i_dec_cw, i_dec_cb, i_dec_bn_g, i_dec_bn_b;
    int i_dec_lin_w, i_dec_lin_b;
    if (in_sizes[24] == DD * DD * 5) { // signature order
        i_dec_ct_w = 24; i_dec_ct_b = 25; i_dec_bn0_g = 26; i_dec_bn0_b = 27;
        i_dec_cw = 28; i_dec_cb = 29; i_dec_bn_g = 30; i_dec_bn_b = 31;
        i_dec_lin_w = 32; i_dec_lin_b = 33;
        i_dec_in_w = 34; i_dec_in_b = 35; i_dec_out_w = 36; i_dec_out_b = 37;
        i_dec_ln1_g = 38; i_dec_ln1_b = 39; i_dec_ff1_w = 40; i_dec_ff1_b = 41;
        i_dec_ff2_w = 42; i_dec_ff2_b = 43; i_dec_ln2_g = 44; i_dec_ln2_b = 45;
    } else { // dict order
        i_dec_in_w = 24; i_dec_in_b = 25; i_dec_out_w = 26; i_dec_out_b = 27;
        i_dec_ln1_g = 28; i_dec_ln1_b = 29; i_dec_ff1_w = 30; i_dec_ff1_b = 31;
        i_dec_ff2_w = 32; i_dec_ff2_b = 33; i_dec_ln2_g = 34; i_dec_ln2_b = 35;
        i_dec_ct_w = 36; i_dec_ct_b = 37; i_dec_bn0_g = 38; i_dec_bn0_b = 39;
        i_dec_cw = 40; i_dec_cb = 41; i_dec_bn_g = 42; i_dec_bn_b = 43;
        i_dec_lin_w = 44; i_dec_lin_b = 45;
    }
    const int i_cross_w = 46, i_cross_b = 47;

    // workspace layout (floats)
    float* ws    = (float*)d_ws;
    float* bufA  = ws + 0;          // 1,572,864
    float* bufB  = ws + 1572864;    // 1,572,864
    float* X     = ws + 3145728;    // 1,572,864
    float* attno = ws + 4718592;    // 1,572,864
    float* proj  = ws + 6291456;    // 1,572,864
    float* qkv   = ws + 7864320;    // 4,718,592  (aliases conv-im2col, convT A_even/A_odd)
    float* sc    = ws + 12582912;   // 6,291,456  (aliases ff)
    float* wr    = ws + 18874368;   // 2,949,120  (aliases W_even/W_odd, cross wcr)
    int*   idxb  = (int*)(ws + 21823488); // 256
    float* out   = (float*)d_out;
    float* lossp = out + BB * TT * DIN;
    float* idxf  = out + BB * TT * DIN + 1;

    hipMemsetAsync(lossp, 0, sizeof(float), stream);

    // ---------------- encoder squasher ----------------
    conv0_enc<<<(BB * 128 * DD + 255) / 256, 256, 0, stream>>>(P[0], P[2], P[3], P[4], P[5], bufA);
    int T = 128;
    for (int i = 0; i < 2; i++) {
        reorder_w<<<(DD * DD * 5 + 255) / 256, 256, 0, stream>>>(P[6] + (size_t)i * DD * DD * 5, wr);
        im2col_rep<<<(int)(((size_t)BB * T * 5 * DD + 255) / 256), 256, 0, stream>>>(bufA, qkv, T);
        gemm_nt<<<dim3(DD / 64, BB * T / 64), 256, 0, stream>>>(qkv, wr, P[7] + i * DD, bufB,
                                                                BB * T, DD, 5 * DD, 2, P[8] + i * DD, P[9] + i * DD, 1, 0);
        maxpool2<<<(BB * (T / 2) * DD + 255) / 256, 256, 0, stream>>>(bufB, bufA, T / 2);
        T /= 2;
    }
    gemm_nt<<<dim3(DD / 64, 256 / 64), 256, 0, stream>>>(bufA, P[10], P[11], X, 256, DD, DD, 0, nullptr, nullptr, 1, 0);
    for (int l = 0; l < LL; l++) {
        run_tlayer(X, qkv, sc, attno, proj,
                   P[12] + (size_t)l * QKVD * DD, P[13] + (size_t)l * QKVD,
                   P[14] + (size_t)l * DD * DD,  P[15] + (size_t)l * DD,
                   P[16] + (size_t)l * DD,       P[17] + (size_t)l * DD,
                   P[18] + (size_t)l * FF_ * DD, P[19] + (size_t)l * FF_,
                   P[20] + (size_t)l * DD * FF_, P[21] + (size_t)l * DD,
                   P[22] + (size_t)l * DD,       P[23] + (size_t)l * DD,
                   32, stream);
    }
    // ---------------- VQ ----------------
    vq_argmin<<<256, 256, 0, stream>>>(X, P[1], idxb, idxf);
    zq_loss<<<(256 * DD + 255) / 256, 256, 0, stream>>>(P[1], idxb, X, bufA, lossp);
    // ---------------- decoder expander: convT as even/odd GEMMs ----------------
    {
        float* We = wr;                       // 768*2304
        float* Wo = wr + (size_t)DD * 3 * DD; // 768*1536
        float* Ae = qkv;                      // 256*2304
        float* Ao = qkv + 256 * 3 * DD;       // 256*1536
        reorder_ctw<<<(DD * DD * 5 + 255) / 256, 256, 0, stream>>>(P[i_dec_ct_w], We, Wo);
        im2colT<<<(256 * 5 * DD + 255) / 256, 256, 0, stream>>>(bufA, Ae, Ao);
        gemm_nt<<<dim3(DD / 64, 4), 256, 0, stream>>>(Ae, We, P[i_dec_ct_b], bufB, 256, DD, 3 * DD, 2,
                                                      P[i_dec_bn0_g], P[i_dec_bn0_b], 2, 0);
        gemm_nt<<<dim3(DD / 64, 4), 256, 0, stream>>>(Ao, Wo, P[i_dec_ct_b], bufB, 256, DD, 2 * DD, 2,
                                                      P[i_dec_bn0_g], P[i_dec_bn0_b], 2, 1);
    }
    T = 64;
    for (int i = 0; i < 2; i++) {
        reorder_w<<<(DD * DD * 5 + 255) / 256, 256, 0, stream>>>(P[i_dec_cw] + (size_t)i * DD * DD * 5, wr);
        im2col_rep<<<(int)(((size_t)BB * T * 5 * DD + 255) / 256), 256, 0, stream>>>(bufB, qkv, T);
        gemm_nt<<<dim3(DD / 64, BB * T / 64), 256, 0, stream>>>(qkv, wr, P[i_dec_cb] + i * DD, bufA,
                                                                BB * T, DD, 5 * DD, 2,
                                                                P[i_dec_bn_g] + i * DD, P[i_dec_bn_b] + i * DD, 1, 0);
        rep2<<<(BB * 2 * T * DD + 255) / 256, 256, 0, stream>>>(bufA, bufB, T);
        T *= 2;
    }
    gemm_nt<<<dim3(DD / 64, 2048 / 64), 256, 0, stream>>>(bufB, P[i_dec_lin_w], P[i_dec_lin_b], X,
                                                          2048, DD, DD, 0, nullptr, nullptr, 1, 0);
    for (int l = 0; l < LL; l++) {
        run_tlayer(X, qkv, sc, attno, proj,
                   P[i_dec_in_w]  + (size_t)l * QKVD * DD, P[i_dec_in_b]  + (size_t)l * QKVD,
                   P[i_dec_out_w] + (size_t)l * DD * DD,   P[i_dec_out_b] + (size_t)l * DD,
                   P[i_dec_ln1_g] + (size_t)l * DD,        P[i_dec_ln1_b] + (size_t)l * DD,
                   P[i_dec_ff1_w] + (size_t)l * FF_ * DD,  P[i_dec_ff1_b] + (size_t)l * FF_,
                   P[i_dec_ff2_w] + (size_t)l * DD * FF_,  P[i_dec_ff2_b] + (size_t)l * DD,
                   P[i_dec_ln2_g] + (size_t)l * DD,        P[i_dec_ln2_b] + (size_t)l * DD,
                   256, stream);
    }
    // ---------------- final cross conv ----------------
    reorder_crossw<<<(DIN * DD * 5 + 255) / 256, 256, 0, stream>>>(P[i_cross_w], wr);
    cross_conv_wave<<<(BB * TT * DIN * 64 + 255) / 256, 256, 0, stream>>>(X, wr, P[i_cross_b], out);
}

// Round 3
// 4697.184 us; speedup vs baseline: 2.2586x; 1.3586x over previous
//
#include <hip/hip_runtime.h>
#include <hip/hip_bf16.h>

// ---- model dims ----
#define BB   8
#define TT   256
#define DIN  53
#define DD   768
#define HH   12
#define DHD  64
#define FF_  3072
#define LL   4
#define KK   1024
#define QKVD 2304
#define BN_F 0.9999950000374997f  // 1/sqrt(1+1e-5)

typedef __attribute__((ext_vector_type(8))) short bf16x8;
typedef __attribute__((ext_vector_type(4))) float f32x4;

__device__ __forceinline__ float lrelu_f(float v) { return v >= 0.f ? v : 0.2f * v; }
__device__ __forceinline__ ushort f2bf(float f) {
    __hip_bfloat16 h = __float2bfloat16(f);
    return *reinterpret_cast<ushort*>(&h);
}

// =============== fp32 tiled GEMM (encoder): C[M,N] = A[M,K] @ W[N,K]^T + bias ===============
// epi: 0 none, 1 gelu(exact), 2 lrelu then eval-BN
__global__ __launch_bounds__(256) void gemm_nt(
    const float* __restrict__ A, const float* __restrict__ W,
    const float* __restrict__ bias, float* __restrict__ C,
    int M, int N, int K, int epi,
    const float* __restrict__ bng, const float* __restrict__ bnb,
    int row_scale, int row_off)
{
    __shared__ float As[16][68];
    __shared__ float Ws[16][68];
    const int bm = blockIdx.y, bn = blockIdx.x;
    const int tid = threadIdx.x;
    const int tx = tid & 15, ty = tid >> 4;
    float acc[4][4] = {{0.f}};
    const float* Ab = A + (size_t)bm * 64 * K;
    const float* Wb = W + (size_t)bn * 64 * K;
    for (int k0 = 0; k0 < K; k0 += 16) {
        #pragma unroll
        for (int i = 0; i < 4; i++) {
            int idx = tid + i * 256;
            int m = idx >> 4, kk = idx & 15;
            As[kk][m] = Ab[(size_t)m * K + k0 + kk];
            Ws[kk][m] = Wb[(size_t)m * K + k0 + kk];
        }
        __syncthreads();
        #pragma unroll
        for (int kk = 0; kk < 16; kk++) {
            float4 a4 = *(const float4*)&As[kk][ty * 4];
            float4 w4 = *(const float4*)&Ws[kk][tx * 4];
            float a[4] = {a4.x, a4.y, a4.z, a4.w};
            float w[4] = {w4.x, w4.y, w4.z, w4.w};
            #pragma unroll
            for (int i = 0; i < 4; i++)
                #pragma unroll
                for (int j = 0; j < 4; j++)
                    acc[i][j] = fmaf(a[i], w[j], acc[i][j]);
        }
        __syncthreads();
    }
    #pragma unroll
    for (int i = 0; i < 4; i++) {
        int row = bm * 64 + ty * 4 + i;
        #pragma unroll
        for (int j = 0; j < 4; j++) {
            int col = bn * 64 + tx * 4 + j;
            float v = acc[i][j] + bias[col];
            if (epi == 1) {
                v = 0.5f * v * (1.0f + erff(v * 0.70710678118654752f));
            } else if (epi == 2) {
                v = lrelu_f(v);
                v = v * (bng[col] * BN_F) + bnb[col];
            }
            C[(size_t)(row * row_scale + row_off) * N + col] = v;
        }
    }
}

// =============== bf16 MFMA GEMM (decoder): C[M,N] = A[M,K] @ W[N,K]^T + bias ===============
// A and W are fp32 in memory; converted to bf16 during LDS staging.
// 128x128 tile, BK=32, 4 waves each computing a 64x64 quadrant (4x4 of 16x16x32 MFMA).
__global__ __launch_bounds__(256) void gemm_bf16(
    const float* __restrict__ A, const float* __restrict__ W,
    const float* __restrict__ bias, float* __restrict__ C,
    int M, int N, int K, int epi,
    const float* __restrict__ bng, const float* __restrict__ bnb,
    int row_scale, int row_off)
{
    __shared__ ushort Asm[128 * 40];
    __shared__ ushort Bsm[128 * 40];
    const int bm = blockIdx.y, bn = blockIdx.x;
    const int tid = threadIdx.x;
    const int w = tid >> 6, l = tid & 63;
    const int wr = w >> 1, wc = w & 1;
    const int l16 = l & 15, k8 = (l >> 4) * 8;

    f32x4 acc[4][4];
    #pragma unroll
    for (int m = 0; m < 4; m++)
        #pragma unroll
        for (int n = 0; n < 4; n++)
            acc[m][n] = (f32x4){0.f, 0.f, 0.f, 0.f};

    const int srow = tid >> 1;
    const int kb = (tid & 1) * 16;
    const float* Ab = A + ((size_t)(bm * 128 + srow)) * K + kb;
    const float* Wb = W + ((size_t)(bn * 128 + srow)) * K + kb;
    ushort* Asw = &Asm[srow * 40 + kb];
    ushort* Bsw = &Bsm[srow * 40 + kb];

    for (int k0 = 0; k0 < K; k0 += 32) {
        float4 a0 = *(const float4*)(Ab + k0);
        float4 a1 = *(const float4*)(Ab + k0 + 4);
        float4 a2 = *(const float4*)(Ab + k0 + 8);
        float4 a3 = *(const float4*)(Ab + k0 + 12);
        float4 b0 = *(const float4*)(Wb + k0);
        float4 b1 = *(const float4*)(Wb + k0 + 4);
        float4 b2 = *(const float4*)(Wb + k0 + 8);
        float4 b3 = *(const float4*)(Wb + k0 + 12);
        union { ushort u[8]; uint4 v; } pa0, pa1, pb0, pb1;
        pa0.u[0] = f2bf(a0.x); pa0.u[1] = f2bf(a0.y); pa0.u[2] = f2bf(a0.z); pa0.u[3] = f2bf(a0.w);
        pa0.u[4] = f2bf(a1.x); pa0.u[5] = f2bf(a1.y); pa0.u[6] = f2bf(a1.z); pa0.u[7] = f2bf(a1.w);
        pa1.u[0] = f2bf(a2.x); pa1.u[1] = f2bf(a2.y); pa1.u[2] = f2bf(a2.z); pa1.u[3] = f2bf(a2.w);
        pa1.u[4] = f2bf(a3.x); pa1.u[5] = f2bf(a3.y); pa1.u[6] = f2bf(a3.z); pa1.u[7] = f2bf(a3.w);
        pb0.u[0] = f2bf(b0.x); pb0.u[1] = f2bf(b0.y); pb0.u[2] = f2bf(b0.z); pb0.u[3] = f2bf(b0.w);
        pb0.u[4] = f2bf(b1.x); pb0.u[5] = f2bf(b1.y); pb0.u[6] = f2bf(b1.z); pb0.u[7] = f2bf(b1.w);
        pb1.u[0] = f2bf(b2.x); pb1.u[1] = f2bf(b2.y); pb1.u[2] = f2bf(b2.z); pb1.u[3] = f2bf(b2.w);
        pb1.u[4] = f2bf(b3.x); pb1.u[5] = f2bf(b3.y); pb1.u[6] = f2bf(b3.z); pb1.u[7] = f2bf(b3.w);
        *(uint4*)Asw = pa0.v;
        *(uint4*)(Asw + 8) = pa1.v;
        *(uint4*)Bsw = pb0.v;
        *(uint4*)(Bsw + 8) = pb1.v;
        __syncthreads();
        bf16x8 af[4], bfr[4];
        #pragma unroll
        for (int m = 0; m < 4; m++)
            af[m] = *(const bf16x8*)&Asm[(wr * 64 + m * 16 + l16) * 40 + k8];
        #pragma unroll
        for (int n = 0; n < 4; n++)
            bfr[n] = *(const bf16x8*)&Bsm[(wc * 64 + n * 16 + l16) * 40 + k8];
        #pragma unroll
        for (int m = 0; m < 4; m++)
            #pragma unroll
            for (int n = 0; n < 4; n++)
                acc[m][n] = __builtin_amdgcn_mfma_f32_16x16x32_bf16(af[m], bfr[n], acc[m][n], 0, 0, 0);
        __syncthreads();
    }
    #pragma unroll
    for (int m = 0; m < 4; m++) {
        int row = bm * 128 + wr * 64 + m * 16 + (l >> 4) * 4;
        #pragma unroll
        for (int n = 0; n < 4; n++) {
            int col = bn * 128 + wc * 64 + n * 16 + l16;
            float bcol = bias[col];
            float g = (epi == 2) ? bng[col] * BN_F : 0.f;
            float s = (epi == 2) ? bnb[col] : 0.f;
            #pragma unroll
            for (int j = 0; j < 4; j++) {
                float v = acc[m][n][j] + bcol;
                if (epi == 1) {
                    v = 0.5f * v * (1.0f + erff(v * 0.70710678118654752f));
                } else if (epi == 2) {
                    v = lrelu_f(v);
                    v = v * g + s;
                }
                C[(size_t)((row + j) * row_scale + row_off) * N + col] = v;
            }
        }
    }
}

// =============== conv0 weight reorder: w[co][ci][k] -> w2[(k*53+ci)*768 + co] ===============
__global__ __launch_bounds__(256) void reorder_c0w(const float* __restrict__ w, float* __restrict__ w2)
{
    int i = blockIdx.x * 256 + threadIdx.x;
    if (i >= DD * DIN * 5) return;
    int k  = i % 5;
    int ci = (i / 5) % DIN;
    int co = i / (5 * DIN);
    w2[(size_t)(k * DIN + ci) * DD + co] = w[i];
}

// =============== encoder first conv: block per (b,t); lanes sweep co (coalesced) ===============
__global__ __launch_bounds__(256) void conv0_enc(
    const float* __restrict__ x, const float* __restrict__ w2, const float* __restrict__ b0,
    const float* __restrict__ g, const float* __restrict__ bb, float* __restrict__ out)
{
    int blk = blockIdx.x;            // 0..1023
    int b = blk >> 7, t = blk & 127;
    int tid = threadIdx.x;
    __shared__ float xs[5 * DIN];
    for (int j = tid; j < 5 * DIN; j += 256) {
        int k = j / DIN, ci = j % DIN;
        int ti = 2 * t - 2 + k;
        ti = ti < 0 ? 0 : (ti > TT - 1 ? TT - 1 : ti);
        xs[j] = x[((size_t)b * TT + ti) * DIN + ci];
    }
    __syncthreads();
    float acc0 = 0.f, acc1 = 0.f, acc2 = 0.f;
    for (int j = 0; j < 5 * DIN; j++) {
        float xv = xs[j];
        const float* wp = w2 + (size_t)j * DD;
        acc0 = fmaf(xv, wp[tid], acc0);
        acc1 = fmaf(xv, wp[tid + 256], acc1);
        acc2 = fmaf(xv, wp[tid + 512], acc2);
    }
    float* op = out + ((size_t)b * 128 + t) * DD;
    int c;
    c = tid;       op[c] = lrelu_f(acc0 + b0[c]) * (g[c] * BN_F) + bb[c];
    c = tid + 256; op[c] = lrelu_f(acc1 + b0[c]) * (g[c] * BN_F) + bb[c];
    c = tid + 512; op[c] = lrelu_f(acc2 + b0[c]) * (g[c] * BN_F) + bb[c];
}

// =============== weight reorder: w[co][ci][k] -> wr[co][k*768+ci] (mid convs) ===============
__global__ __launch_bounds__(256) void reorder_w(const float* __restrict__ w, float* __restrict__ wr)
{
    int i = blockIdx.x * 256 + threadIdx.x;
    if (i >= DD * DD * 5) return;
    int k  = i % 5;
    int t  = i / 5;
    int ci = t % DD;
    int co = t / DD;
    wr[(size_t)co * (5 * DD) + k * DD + ci] = w[i];
}

// =============== im2col (stride1, pad2, replicate) ===============
__global__ __launch_bounds__(256) void im2col_rep(const float* __restrict__ x, float* __restrict__ xc, int T)
{
    size_t i = (size_t)blockIdx.x * 256 + threadIdx.x;
    size_t total = (size_t)BB * T * 5 * DD;
    if (i >= total) return;
    int c = (int)(i % DD);
    size_t t2 = i / DD;
    int k = (int)(t2 % 5);
    size_t t3 = t2 / 5;
    int t = (int)(t3 % T);
    int b = (int)(t3 / T);
    int ti = t - 2 + k;
    ti = ti < 0 ? 0 : (ti > T - 1 ? T - 1 : ti);
    xc[i] = x[((size_t)b * T + ti) * DD + c];
}

// =============== maxpool over time pairs ===============
__global__ __launch_bounds__(256) void maxpool2(const float* __restrict__ in, float* __restrict__ out, int To)
{
    int i = blockIdx.x * 256 + threadIdx.x;
    if (i >= BB * To * DD) return;
    int c = i % DD;
    int t = (i / DD) % To;
    int b = i / (DD * To);
    const float* p = in + ((size_t)b * 2 * To + 2 * t) * DD + c;
    out[i] = fmaxf(p[0], p[DD]);
}

// =============== repeat_interleave(2) over time ===============
__global__ __launch_bounds__(256) void rep2(const float* __restrict__ in, float* __restrict__ out, int Ti)
{
    int i = blockIdx.x * 256 + threadIdx.x;
    if (i >= BB * 2 * Ti * DD) return;
    int c = i % DD;
    int t = (i / DD) % (2 * Ti);
    int b = i / (DD * 2 * Ti);
    out[i] = in[((size_t)b * Ti + (t >> 1)) * DD + c];
}

// =============== attention naive (S=32 only, encoder) ===============
__global__ __launch_bounds__(256) void attn_scores(const float* __restrict__ qkv, float* __restrict__ sc, int S)
{
    int i = blockIdx.x * 256 + threadIdx.x;
    if (i >= BB * HH * S * S) return;
    int k = i % S;
    int t = i / S;
    int q = t % S; t /= S;
    int h = t % HH;
    int b = t / HH;
    const float* qp = qkv + ((size_t)(b * S + q)) * QKVD + h * DHD;
    const float* kp = qkv + ((size_t)(b * S + k)) * QKVD + DD + h * DHD;
    float s = 0.f;
    #pragma unroll
    for (int d = 0; d < DHD; d++) s = fmaf(qp[d], kp[d], s);
    sc[i] = s * 0.125f;
}

__global__ __launch_bounds__(256) void attn_out(const float* __restrict__ sc, const float* __restrict__ qkv,
                                                float* __restrict__ o, int S)
{
    int i = blockIdx.x * 256 + threadIdx.x;
    if (i >= BB * S * DD) return;
    int j = i % DD;
    int t = i / DD;
    int q = t % S;
    int b = t / S;
    int h = j >> 6;
    const float* p = sc + (((size_t)(b * HH + h) * S + q)) * S;
    const float* vp = qkv + 2 * DD + j + (size_t)b * S * QKVD;
    float s = 0.f;
    for (int k = 0; k < S; k++) s = fmaf(p[k], vp[(size_t)k * QKVD], s);
    o[(size_t)(b * S + q) * DD + j] = s;
}

// =============== batched scores GEMM (S=256) ===============
__global__ __launch_bounds__(256) void attn_scores_gemm(const float* __restrict__ qkv, float* __restrict__ sc)
{
    const int S = 256;
    int bh = blockIdx.z;
    int b = bh / HH, h = bh % HH;
    const float* Qb = qkv + (size_t)b * S * QKVD + h * DHD;
    const float* Kb = qkv + (size_t)b * S * QKVD + DD + h * DHD;
    __shared__ float As[64][65];
    __shared__ float Ws[64][65];
    int tid = threadIdx.x;
    int tx = tid & 15, ty = tid >> 4;
    #pragma unroll
    for (int i = 0; i < 16; i++) {
        int idx = tid + i * 256;
        int m = idx >> 6, kk = idx & 63;
        As[m][kk] = Qb[(size_t)(blockIdx.y * 64 + m) * QKVD + kk];
        Ws[m][kk] = Kb[(size_t)(blockIdx.x * 64 + m) * QKVD + kk];
    }
    __syncthreads();
    float acc[4][4] = {{0.f}};
    #pragma unroll 4
    for (int kk = 0; kk < 64; kk++) {
        float a[4], w[4];
        #pragma unroll
        for (int i = 0; i < 4; i++) a[i] = As[ty * 4 + i][kk];
        #pragma unroll
        for (int j = 0; j < 4; j++) w[j] = Ws[tx * 4 + j][kk];
        #pragma unroll
        for (int i = 0; i < 4; i++)
            #pragma unroll
            for (int j = 0; j < 4; j++)
                acc[i][j] = fmaf(a[i], w[j], acc[i][j]);
    }
    #pragma unroll
    for (int i = 0; i < 4; i++) {
        int q = blockIdx.y * 64 + ty * 4 + i;
        #pragma unroll
        for (int j = 0; j < 4; j++) {
            int k = blockIdx.x * 64 + tx * 4 + j;
            sc[((size_t)bh * S + q) * S + k] = acc[i][j] * 0.125f;
        }
    }
}

// =============== batched AV GEMM (S=256) ===============
__global__ __launch_bounds__(256) void attn_av_gemm(const float* __restrict__ sc, const float* __restrict__ qkv,
                                                    float* __restrict__ o)
{
    const int S = 256;
    int bh = blockIdx.z;
    int b = bh / HH, h = bh % HH;
    const float* Vb = qkv + (size_t)b * S * QKVD + 2 * DD + h * DHD;
    const float* Ab = sc + (size_t)bh * S * S + (size_t)blockIdx.y * 64 * S;
    __shared__ float As[64][65];
    __shared__ float Bs[64][65];
    int tid = threadIdx.x;
    int tx = tid & 15, ty = tid >> 4;
    float acc[4][4] = {{0.f}};
    for (int k0 = 0; k0 < S; k0 += 64) {
        #pragma unroll
        for (int i = 0; i < 16; i++) {
            int idx = tid + i * 256;
            int m = idx >> 6, kk = idx & 63;
            As[m][kk] = Ab[(size_t)m * S + k0 + kk];
            Bs[m][kk] = Vb[(size_t)(k0 + m) * QKVD + kk];
        }
        __syncthreads();
        #pragma unroll 4
        for (int kk = 0; kk < 64; kk++) {
            float a[4], w[4];
            #pragma unroll
            for (int i = 0; i < 4; i++) a[i] = As[ty * 4 + i][kk];
            #pragma unroll
            for (int j = 0; j < 4; j++) w[j] = Bs[kk][tx * 4 + j];
            #pragma unroll
            for (int i = 0; i < 4; i++)
                #pragma unroll
                for (int j = 0; j < 4; j++)
                    acc[i][j] = fmaf(a[i], w[j], acc[i][j]);
        }
        __syncthreads();
    }
    #pragma unroll
    for (int i = 0; i < 4; i++) {
        int q = blockIdx.y * 64 + ty * 4 + i;
        #pragma unroll
        for (int j = 0; j < 4; j++) {
            int n = tx * 4 + j;
            o[((size_t)b * S + q) * DD + h * DHD + n] = acc[i][j];
        }
    }
}

__global__ __launch_bounds__(256) void softmax_rows(float* __restrict__ sc, int S)
{
    int row = blockIdx.x;
    float* p = sc + (size_t)row * S;
    int tid = threadIdx.x;
    __shared__ float red[256];
    float m = -1e30f;
    for (int d = tid; d < S; d += 256) m = fmaxf(m, p[d]);
    red[tid] = m; __syncthreads();
    for (int s = 128; s > 0; s >>= 1) { if (tid < s) red[tid] = fmaxf(red[tid], red[tid + s]); __syncthreads(); }
    m = red[0]; __syncthreads();
    float sum = 0.f;
    for (int d = tid; d < S; d += 256) { float e = expf(p[d] - m); p[d] = e; sum += e; }
    red[tid] = sum; __syncthreads();
    for (int s = 128; s > 0; s >>= 1) { if (tid < s) red[tid] += red[tid + s]; __syncthreads(); }
    float inv = 1.0f / red[0];
    for (int d = tid; d < S; d += 256) p[d] *= inv;
}

// =============== x = LN(x + y) * g + b, in place on x ===============
__global__ __launch_bounds__(256) void add_ln(float* __restrict__ x, const float* __restrict__ y,
                                              const float* __restrict__ g, const float* __restrict__ bb)
{
    int row = blockIdx.x;
    int tid = threadIdx.x;
    __shared__ float buf[DD];
    __shared__ float red[256];
    float* xp = x + (size_t)row * DD;
    const float* yp = y + (size_t)row * DD;
    float s = 0.f;
    for (int d = tid; d < DD; d += 256) { float v = xp[d] + yp[d]; buf[d] = v; s += v; }
    red[tid] = s; __syncthreads();
    for (int k = 128; k > 0; k >>= 1) { if (tid < k) red[tid] += red[tid + k]; __syncthreads(); }
    float mean = red[0] * (1.0f / DD);
    __syncthreads();
    float s2 = 0.f;
    for (int d = tid; d < DD; d += 256) { float v = buf[d] - mean; s2 += v * v; }
    red[tid] = s2; __syncthreads();
    for (int k = 128; k > 0; k >>= 1) { if (tid < k) red[tid] += red[tid + k]; __syncthreads(); }
    float rstd = rsqrtf(red[0] * (1.0f / DD) + 1e-5f);
    for (int d = tid; d < DD; d += 256) xp[d] = (buf[d] - mean) * rstd * g[d] + bb[d];
}

// =============== VQ argmin ===============
__global__ __launch_bounds__(256) void vq_argmin(const float* __restrict__ h, const float* __restrict__ cb,
                                                 int* __restrict__ idx_out, float* __restrict__ idx_f)
{
    int row = blockIdx.x;
    int tid = threadIdx.x;
    __shared__ float z[DD];
    const float* hp = h + (size_t)row * DD;
    for (int d = tid; d < DD; d += 256) z[d] = hp[d];
    __syncthreads();
    float best = 3.4e38f;
    int bi = 0x7fffffff;
    for (int c = tid; c < KK; c += 256) {
        const float* e = cb + (size_t)c * DD;
        float acc = 0.f;
        for (int d = 0; d < DD; d++) { float ev = e[d]; acc = fmaf(ev, ev - 2.f * z[d], acc); }
        if (acc < best) { best = acc; bi = c; }
    }
    __shared__ float bred[256];
    __shared__ int   ired[256];
    bred[tid] = best; ired[tid] = bi; __syncthreads();
    for (int s = 128; s > 0; s >>= 1) {
        if (tid < s) {
            float o = bred[tid + s]; int oi = ired[tid + s];
            if (o < bred[tid] || (o == bred[tid] && oi < ired[tid])) { bred[tid] = o; ired[tid] = oi; }
        }
        __syncthreads();
    }
    if (tid == 0) { idx_out[row] = ired[0]; idx_f[row] = (float)ired[0]; }
}

// =============== zq gather + VQ loss ===============
__global__ __launch_bounds__(256) void zq_loss(const float* __restrict__ cb, const int* __restrict__ idx,
                                               const float* __restrict__ h, float* __restrict__ zq,
                                               float* __restrict__ loss)
{
    int i = blockIdx.x * 256 + threadIdx.x;
    float d2 = 0.f;
    if (i < 256 * DD) {
        int r = i / DD, d = i % DD;
        float q = cb[(size_t)idx[r] * DD + d];
        zq[i] = q;
        float df = q - h[i];
        d2 = df * df;
    }
    __shared__ float red[256];
    red[threadIdx.x] = d2; __syncthreads();
    for (int s = 128; s > 0; s >>= 1) { if (threadIdx.x < s) red[threadIdx.x] += red[threadIdx.x + s]; __syncthreads(); }
    if (threadIdx.x == 0) atomicAdd(loss, red[0] * (1.25f / (256.0f * (float)DD)));
}

// =============== convT weight reorder ===============
__global__ __launch_bounds__(256) void reorder_ctw(const float* __restrict__ wt, float* __restrict__ We,
                                                   float* __restrict__ Wo)
{
    int i = blockIdx.x * 256 + threadIdx.x;
    if (i >= DD * DD * 5) return;
    int k  = i % 5;
    int co = (i / 5) % DD;
    int ci = i / (5 * DD);
    float v = wt[i];
    if ((k & 1) == 0) We[(size_t)co * (3 * DD) + (k >> 1) * DD + ci] = v;
    else             Wo[(size_t)co * (2 * DD) + (k >> 1) * DD + ci] = v;
}

// =============== convT im2col ===============
__global__ __launch_bounds__(256) void im2colT(const float* __restrict__ zq, float* __restrict__ Ae,
                                               float* __restrict__ Ao)
{
    int i = blockIdx.x * 256 + threadIdx.x;
    const int TE = 256 * 3 * DD;
    const int TO = 256 * 2 * DD;
    if (i < TE) {
        int r = i / (3 * DD), c = i % (3 * DD);
        int j = c / DD, ci = c % DD;
        int b = r >> 5, u = r & 31;
        int s = u + 1 - j;
        Ae[i] = (s >= 0 && s < 32) ? zq[((size_t)(b * 32 + s)) * DD + ci] : 0.f;
    } else if (i < TE + TO) {
        int i2 = i - TE;
        int r = i2 / (2 * DD), c = i2 % (2 * DD);
        int j = c / DD, ci = c % DD;
        int b = r >> 5, u = r & 31;
        int s = u + 1 - j;
        Ao[i2] = (s >= 0 && s < 32) ? zq[((size_t)(b * 32 + s)) * DD + ci] : 0.f;
    }
}

// =============== cross weight reorder ===============
__global__ __launch_bounds__(256) void reorder_crossw(const float* __restrict__ w, float* __restrict__ wcr)
{
    int i = blockIdx.x * 256 + threadIdx.x;
    if (i >= DIN * DD * 5) return;
    int k  = i % 5;
    int ci = (i / 5) % DD;
    int co = i / (5 * DD);
    wcr[(size_t)co * (5 * DD) + k * DD + ci] = w[i];
}

// =============== cross conv: one wave per output ===============
__global__ __launch_bounds__(256) void cross_conv_wave(const float* __restrict__ y, const float* __restrict__ wcr,
                                                       const float* __restrict__ b0, float* __restrict__ out)
{
    int gwid = (blockIdx.x * 256 + threadIdx.x) >> 6;
    int lane = threadIdx.x & 63;
    if (gwid >= BB * TT * DIN) return;
    int co = gwid % DIN;
    int t  = (gwid / DIN) % TT;
    int b  = gwid / (DIN * TT);
    const float* wp = wcr + (size_t)co * (5 * DD);
    const float* yb = y + (size_t)b * TT * DD;
    float acc = 0.f;
    int ci = lane, k = 0;
    #pragma unroll 4
    for (int j = 0; j < 60; j++) {
        int ti = t - 2 + k;
        if (ti >= 0 && ti < TT)
            acc = fmaf(yb[(size_t)ti * DD + ci], wp[lane + 64 * j], acc);
        ci += 64;
        if (ci >= DD) { ci -= DD; k++; }
    }
    #pragma unroll
    for (int off = 32; off > 0; off >>= 1) acc += __shfl_down(acc, off);
    if (lane == 0) out[gwid] = acc + b0[co];
}

// ================= host orchestration =================
static void run_tlayer(float* X, float* qkv, float* sc, float* attno, float* proj,
                       const float* in_w, const float* in_b, const float* out_w, const float* out_b,
                       const float* g1, const float* b1, const float* f1w, const float* f1b,
                       const float* f2w, const float* f2b, const float* g2, const float* b2,
                       int S, hipStream_t stream)
{
    int M = BB * S;
    if (S == 256) {
        gemm_bf16<<<dim3(QKVD / 128, M / 128), 256, 0, stream>>>(X, in_w, in_b, qkv, M, QKVD, DD, 0, nullptr, nullptr, 1, 0);
        attn_scores_gemm<<<dim3(4, 4, BB * HH), 256, 0, stream>>>(qkv, sc);
        softmax_rows<<<BB * HH * S, 256, 0, stream>>>(sc, S);
        attn_av_gemm<<<dim3(1, 4, BB * HH), 256, 0, stream>>>(sc, qkv, attno);
        gemm_bf16<<<dim3(DD / 128, M / 128), 256, 0, stream>>>(attno, out_w, out_b, proj, M, DD, DD, 0, nullptr, nullptr, 1, 0);
        add_ln<<<M, 256, 0, stream>>>(X, proj, g1, b1);
        gemm_bf16<<<dim3(FF_ / 128, M / 128), 256, 0, stream>>>(X, f1w, f1b, sc, M, FF_, DD, 1, nullptr, nullptr, 1, 0);
        gemm_bf16<<<dim3(DD / 128, M / 128), 256, 0, stream>>>(sc, f2w, f2b, proj, M, DD, FF_, 0, nullptr, nullptr, 1, 0);
        add_ln<<<M, 256, 0, stream>>>(X, proj, g2, b2);
    } else {
        gemm_nt<<<dim3(QKVD / 64, M / 64), 256, 0, stream>>>(X, in_w, in_b, qkv, M, QKVD, DD, 0, nullptr, nullptr, 1, 0);
        attn_scores<<<(BB * HH * S * S + 255) / 256, 256, 0, stream>>>(qkv, sc, S);
        softmax_rows<<<BB * HH * S, 256, 0, stream>>>(sc, S);
        attn_out<<<(M * DD + 255) / 256, 256, 0, stream>>>(sc, qkv, attno, S);
        gemm_nt<<<dim3(DD / 64, M / 64), 256, 0, stream>>>(attno, out_w, out_b, proj, M, DD, DD, 0, nullptr, nullptr, 1, 0);
        add_ln<<<M, 256, 0, stream>>>(X, proj, g1, b1);
        gemm_nt<<<dim3(FF_ / 64, M / 64), 256, 0, stream>>>(X, f1w, f1b, sc, M, FF_, DD, 1, nullptr, nullptr, 1, 0);
        gemm_nt<<<dim3(DD / 64, M / 64), 256, 0, stream>>>(sc, f2w, f2b, proj, M, DD, FF_, 0, nullptr, nullptr, 1, 0);
        add_ln<<<M, 256, 0, stream>>>(X, proj, g2, b2);
    }
}

extern "C" void kernel_launch(void* const* d_in, const int* in_sizes, int n_in,
                              void* d_out, int out_size, void* d_ws, size_t ws_size,
                              hipStream_t stream)
{
    const float* P[48];
    for (int i = 0; i < 48 && i < n_in; i++) P[i] = (const float*)d_in[i];

    int i_dec_in_w, i_dec_in_b, i_dec_out_w, i_dec_out_b, i_dec_ln1_g, i_dec_ln1_b;
    int i_dec_ff1_w, i_dec_ff1_b, i_dec_ff2_w, i_dec_ff2_b, i_dec_ln2_g, i_dec_ln2_b;
    int i_dec_ct_w, i_dec_ct_b, i_dec_bn0_g, i_dec_bn0_b, i_dec_cw, i_dec_cb, i_dec_bn_g, i_dec_bn_b;
    int i_dec_lin_w, i_dec_lin_b;
    if (in_sizes[24] == DD * DD * 5) { // signature order
        i_dec_ct_w = 24; i_dec_ct_b = 25; i_dec_bn0_g = 26; i_dec_bn0_b = 27;
        i_dec_cw = 28; i_dec_cb = 29; i_dec_bn_g = 30; i_dec_bn_b = 31;
        i_dec_lin_w = 32; i_dec_lin_b = 33;
        i_dec_in_w = 34; i_dec_in_b = 35; i_dec_out_w = 36; i_dec_out_b = 37;
        i_dec_ln1_g = 38; i_dec_ln1_b = 39; i_dec_ff1_w = 40; i_dec_ff1_b = 41;
        i_dec_ff2_w = 42; i_dec_ff2_b = 43; i_dec_ln2_g = 44; i_dec_ln2_b = 45;
    } else { // dict order
        i_dec_in_w = 24; i_dec_in_b = 25; i_dec_out_w = 26; i_dec_out_b = 27;
        i_dec_ln1_g = 28; i_dec_ln1_b = 29; i_dec_ff1_w = 30; i_dec_ff1_b = 31;
        i_dec_ff2_w = 32; i_dec_ff2_b = 33; i_dec_ln2_g = 34; i_dec_ln2_b = 35;
        i_dec_ct_w = 36; i_dec_ct_b = 37; i_dec_bn0_g = 38; i_dec_bn0_b = 39;
        i_dec_cw = 40; i_dec_cb = 41; i_dec_bn_g = 42; i_dec_bn_b = 43;
        i_dec_lin_w = 44; i_dec_lin_b = 45;
    }
    const int i_cross_w = 46, i_cross_b = 47;

    // workspace layout (floats)
    float* ws    = (float*)d_ws;
    float* bufA  = ws + 0;          // 1,572,864
    float* bufB  = ws + 1572864;    // 1,572,864
    float* X     = ws + 3145728;    // 1,572,864
    float* attno = ws + 4718592;    // 1,572,864
    float* proj  = ws + 6291456;    // 1,572,864
    float* qkv   = ws + 7864320;    // 4,718,592  (aliases conv-im2col, convT A_even/A_odd)
    float* sc    = ws + 12582912;   // 6,291,456  (aliases ff)
    float* wr    = ws + 18874368;   // 2,949,120  (aliases W_even/W_odd, cross wcr, conv0 w2)
    int*   idxb  = (int*)(ws + 21823488); // 256
    float* out   = (float*)d_out;
    float* lossp = out + BB * TT * DIN;
    float* idxf  = out + BB * TT * DIN + 1;

    hipMemsetAsync(lossp, 0, sizeof(float), stream);

    // ---------------- encoder squasher ----------------
    reorder_c0w<<<(DD * DIN * 5 + 255) / 256, 256, 0, stream>>>(P[2], wr);
    conv0_enc<<<BB * 128, 256, 0, stream>>>(P[0], wr, P[3], P[4], P[5], bufA);
    int T = 128;
    for (int i = 0; i < 2; i++) {
        reorder_w<<<(DD * DD * 5 + 255) / 256, 256, 0, stream>>>(P[6] + (size_t)i * DD * DD * 5, wr);
        im2col_rep<<<(int)(((size_t)BB * T * 5 * DD + 255) / 256), 256, 0, stream>>>(bufA, qkv, T);
        gemm_nt<<<dim3(DD / 64, BB * T / 64), 256, 0, stream>>>(qkv, wr, P[7] + i * DD, bufB,
                                                                BB * T, DD, 5 * DD, 2, P[8] + i * DD, P[9] + i * DD, 1, 0);
        maxpool2<<<(BB * (T / 2) * DD + 255) / 256, 256, 0, stream>>>(bufB, bufA, T / 2);
        T /= 2;
    }
    gemm_nt<<<dim3(DD / 64, 256 / 64), 256, 0, stream>>>(bufA, P[10], P[11], X, 256, DD, DD, 0, nullptr, nullptr, 1, 0);
    for (int l = 0; l < LL; l++) {
        run_tlayer(X, qkv, sc, attno, proj,
                   P[12] + (size_t)l * QKVD * DD, P[13] + (size_t)l * QKVD,
                   P[14] + (size_t)l * DD * DD,  P[15] + (size_t)l * DD,
                   P[16] + (size_t)l * DD,       P[17] + (size_t)l * DD,
                   P[18] + (size_t)l * FF_ * DD, P[19] + (size_t)l * FF_,
                   P[20] + (size_t)l * DD * FF_, P[21] + (size_t)l * DD,
                   P[22] + (size_t)l * DD,       P[23] + (size_t)l * DD,
                   32, stream);
    }
    // ---------------- VQ ----------------
    vq_argmin<<<256, 256, 0, stream>>>(X, P[1], idxb, idxf);
    zq_loss<<<(256 * DD + 255) / 256, 256, 0, stream>>>(P[1], idxb, X, bufA, lossp);
    // ---------------- decoder expander: convT as even/odd GEMMs (bf16) ----------------
    {
        float* We = wr;                       // 768*2304
        float* Wo = wr + (size_t)DD * 3 * DD; // 768*1536
        float* Ae = qkv;                      // 256*2304
        float* Ao = qkv + 256 * 3 * DD;       // 256*1536
        reorder_ctw<<<(DD * DD * 5 + 255) / 256, 256, 0, stream>>>(P[i_dec_ct_w], We, Wo);
        im2colT<<<(256 * 5 * DD + 255) / 256, 256, 0, stream>>>(bufA, Ae, Ao);
        gemm_bf16<<<dim3(DD / 128, 2), 256, 0, stream>>>(Ae, We, P[i_dec_ct_b], bufB, 256, DD, 3 * DD, 2,
                                                         P[i_dec_bn0_g], P[i_dec_bn0_b], 2, 0);
        gemm_bf16<<<dim3(DD / 128, 2), 256, 0, stream>>>(Ao, Wo, P[i_dec_ct_b], bufB, 256, DD, 2 * DD, 2,
                                                         P[i_dec_bn0_g], P[i_dec_bn0_b], 2, 1);
    }
    T = 64;
    for (int i = 0; i < 2; i++) {
        reorder_w<<<(DD * DD * 5 + 255) / 256, 256, 0, stream>>>(P[i_dec_cw] + (size_t)i * DD * DD * 5, wr);
        im2col_rep<<<(int)(((size_t)BB * T * 5 * DD + 255) / 256), 256, 0, stream>>>(bufB, qkv, T);
        gemm_bf16<<<dim3(DD / 128, BB * T / 128), 256, 0, stream>>>(qkv, wr, P[i_dec_cb] + i * DD, bufA,
                                                                    BB * T, DD, 5 * DD, 2,
                                                                    P[i_dec_bn_g] + i * DD, P[i_dec_bn_b] + i * DD, 1, 0);
        rep2<<<(BB * 2 * T * DD + 255) / 256, 256, 0, stream>>>(bufA, bufB, T);
        T *= 2;
    }
    gemm_bf16<<<dim3(DD / 128, 2048 / 128), 256, 0, stream>>>(bufB, P[i_dec_lin_w], P[i_dec_lin_b], X,
                                                              2048, DD, DD, 0, nullptr, nullptr, 1, 0);
    for (int l = 0; l < LL; l++) {
        run_tlayer(X, qkv, sc, attno, proj,
                   P[i_dec_in_w]  + (size_t)l * QKVD * DD, P[i_dec_in_b]  + (size_t)l * QKVD,
                   P[i_dec_out_w] + (size_t)l * DD * DD,   P[i_dec_out_b] + (size_t)l * DD,
                   P[i_dec_ln1_g] + (size_t)l * DD,        P[i_dec_ln1_b] + (size_t)l * DD,
                   P[i_dec_ff1_w] + (size_t)l * FF_ * DD,  P[i_dec_ff1_b] + (size_t)l * FF_,
                   P[i_dec_ff2_w] + (size_t)l * DD * FF_,  P[i_dec_ff2_b] + (size_t)l * DD,
                   P[i_dec_ln2_g] + (size_t)l * DD,        P[i_dec_ln2_b] + (size_t)l * DD,
                   256, stream);
    }
    // ---------------- final cross conv ----------------
    reorder_crossw<<<(DIN * DD * 5 + 255) / 256, 256, 0, stream>>>(P[i_cross_w], wr);
    cross_conv_wave<<<(BB * TT * DIN * 64 + 255) / 256, 256, 0, stream>>>(X, wr, P[i_cross_b], out);
}